// Round 4
// baseline (73.905 us; speedup 1.0000x reference)
//
#include <hip/hip_runtime.h>
#include <math.h>

#define N_ 2048
#define K_ 512
#define J_ 256
#define KC 64     // k-chunk per wave (8 waves cover K=512)
#define NPW 16    // n rows per block

typedef float f32x16 __attribute__((ext_vector_type(16)));

// 2 muls + 1 max3 + 1 min3 per 2 products = 2.0 VALU ops/product.
#define MAX3(acc, a, b) asm("v_max3_f32 %0, %0, %1, %2" : "+v"(acc) : "v"(a), "v"(b))
#define MIN3(acc, a, b) asm("v_min3_f32 %0, %0, %1, %2" : "+v"(acc) : "v"(a), "v"(b))

// Grid 512 blocks x 512 threads (8 waves), __launch_bounds__(512,4):
// 2 blocks/CU, 16 waves/CU, 4/SIMD.
// Flipped operand roles vs previous rounds:
//   lane = j  -> w[j][k-chunk] loaded ONCE into VGPRs (64 regs), never reloaded;
//   x[n][k-chunk] is the wave-uniform operand, streamed via s_load_dwordx16.
// NO barriers in the main loop: the 8 waves (one per k-chunk) run independently,
// so SMEM stalls decorrelate across the CU instead of bursting in lockstep.
// End: one __syncthreads + LDS combine over the 8 k-chunks, coalesced store.
__global__ __launch_bounds__(512, 4) void mam_fused5(
    const float* __restrict__ x, const float* __restrict__ w,
    const float* __restrict__ bias, float* __restrict__ out)
{
    __shared__ float cmb[8][NPW][128];   // [kc][n][ mx(64) | mn(64) ] = 64 KB

    const int t    = threadIdx.x;
    const int lane = t & 63;
    const int kc   = __builtin_amdgcn_readfirstlane(t >> 6);   // wave id = k-chunk 0..7

    // XCD-chunked bijective swizzle (512 = 8 * 64): per XCD ~0.5 MB of x + all of w.
    const int wg0 = (int)blockIdx.x;
    const int wg  = (wg0 & 7) * 64 + (wg0 >> 3);
    const int jb  = wg & 3;             // j-block 0..3 (64 j each)
    const int ng  = wg >> 2;            // n-group 0..127 (16 n each)

    const int j   = jb * 64 + lane;     // this lane's output column
    const int n0  = ng * NPW;

    // w fragment: lane's j-row, wave's k-chunk: 64 floats -> 16 float4 VGPRs.
    // Per-lane rows are 2KB apart (uncoalesced) but every fetched line is fully
    // consumed; one-time cost, latency overlapped with the first x s_loads.
    float4 wreg[16];
    {
        const float4* wp = (const float4*)(w + (size_t)j * K_ + kc * KC);
#pragma unroll
        for (int i = 0; i < 16; ++i) wreg[i] = wp[i];
    }

    const float* xb = x + (size_t)n0 * K_ + kc * KC;   // uniform s_load base

    float mxv[NPW], mnv[NPW];
#pragma unroll
    for (int n = 0; n < NPW; ++n) { mxv[n] = -__builtin_inff(); mnv[n] = __builtin_inff(); }

    // Main loop: per n-row, 4 s_load_dwordx16 (x: 64 floats -> 64 SGPRs, free
    // src0 operands) + lgkmcnt(0) + 128 VALU inst. No barriers, no LDS.
#pragma unroll
    for (int n = 0; n < NPW; ++n) {
        f32x16 xv[4];
        asm volatile(
            "s_load_dwordx16 %0, %4, %5\n\t"
            "s_load_dwordx16 %1, %4, %6\n\t"
            "s_load_dwordx16 %2, %4, %7\n\t"
            "s_load_dwordx16 %3, %4, %8\n\t"
            "s_waitcnt lgkmcnt(0)"
            : "=&s"(xv[0]), "=&s"(xv[1]), "=&s"(xv[2]), "=&s"(xv[3])
            : "s"(xb), "i"(n * 2048 + 0), "i"(n * 2048 + 64),
              "i"(n * 2048 + 128), "i"(n * 2048 + 192));
#pragma unroll
        for (int i = 0; i < 16; ++i) {
            const float p0 = wreg[i].x * xv[i >> 2][(i & 3) * 4 + 0];
            const float p1 = wreg[i].y * xv[i >> 2][(i & 3) * 4 + 1];
            const float p2 = wreg[i].z * xv[i >> 2][(i & 3) * 4 + 2];
            const float p3 = wreg[i].w * xv[i >> 2][(i & 3) * 4 + 3];
            MAX3(mxv[n], p0, p1); MAX3(mxv[n], p2, p3);
            MIN3(mnv[n], p0, p1); MIN3(mnv[n], p2, p3);
        }
    }

    // Combine the 8 k-chunks. Writes/reads are 2-way bank aliased (free).
#pragma unroll
    for (int n = 0; n < NPW; ++n) {
        cmb[kc][n][lane]      = mxv[n];
        cmb[kc][n][64 + lane] = mnv[n];
    }
    __syncthreads();

    const float bj = bias[j];
#pragma unroll
    for (int u = 0; u < 2; ++u) {
        const int n = kc * 2 + u;        // wave kc owns n-pair {2kc, 2kc+1}
        float a = cmb[0][n][lane];
        float b = cmb[0][n][64 + lane];
#pragma unroll
        for (int c = 1; c < 8; ++c) {
            a = fmaxf(a, cmb[c][n][lane]);
            b = fminf(b, cmb[c][n][64 + lane]);
        }
        out[(size_t)(n0 + n) * J_ + j] = a + b + bj;   // 256B coalesced per wave
    }
}

extern "C" void kernel_launch(void* const* d_in, const int* in_sizes, int n_in,
                              void* d_out, int out_size, void* d_ws, size_t ws_size,
                              hipStream_t stream) {
    const float* x    = (const float*)d_in[0];
    const float* w    = (const float*)d_in[1];
    const float* bias = (const float*)d_in[2];
    float* out = (float*)d_out;

    dim3 grid(512);   // 4 j-blocks x 128 n-groups, XCD-swizzled in-kernel
    mam_fused5<<<grid, 512, 0, stream>>>(x, w, bias, out);
}